// Round 16
// baseline (338.702 us; speedup 1.0000x reference)
//
#include <hip/hip_runtime.h>
#include <math.h>

// ---------------- problem constants ----------------
constexpr int Bc = 2, Cc = 64, Nc = 50000, Kc = 8;
constexpr int PT = 16;                       // points per wave (MFMA M dim)
constexpr int WPB = 2;                       // independent waves per block (no barriers)
constexpr int NTILE = (Bc * Nc) / PT;        // 6250
constexpr int NBLK2 = NTILE / WPB;           // 3125, exact

// ---------------- ws byte layout (same as round 8) ----------------
constexpr int BIAS_PH = 16;                  // f32[64]
constexpr int BIAS_N1 = 272;                 // f32[64]
constexpr int BIAS_DL = 528;                 // f32[32] (sv folded, padded)
constexpr int B_PH  = 1024;                  // 12 frags * 1KB
constexpr int B_N1  = 13312;                 // 12 frags
constexpr int B_DH  = 25600;                 // 6 frags (delta hi)
constexpr int B_DLO = 31744;                 // 6 frags (delta lo)
constexpr int B_N2  = 37888;                 // 72 frags -> ends 111616
constexpr size_t XT_BYTE = 262144;           // bf16 volume starts here
constexpr size_t XT_USHORTS = (size_t)Bc * 64 * 64 * 64 * 64;

using bf16x8 = __attribute__((ext_vector_type(8))) short;
using f32x4  = __attribute__((ext_vector_type(4))) float;

// ---------------- helpers ----------------
__device__ __forceinline__ float gelu_exact(float v) {
    return 0.5f * v * (1.0f + erff(v * 0.70710678118654752f));
}
__device__ __forceinline__ ushort f2bf(float f) {           // RNE f32 -> bf16 bits
    unsigned u = __float_as_uint(f);
    unsigned r = (u + 0x7FFFu + ((u >> 16) & 1u)) >> 16;
    return (ushort)r;
}
__device__ __forceinline__ float bf2f(ushort u) {
    return __uint_as_float(((unsigned)u) << 16);
}
__device__ __forceinline__ float tri8(float v000, float v001, float v010, float v011,
                                      float v100, float v101, float v110, float v111,
                                      float fx, float fy, float fz) {
    float c00 = fmaf(fx, v001 - v000, v000);
    float c01 = fmaf(fx, v011 - v010, v010);
    float c10 = fmaf(fx, v101 - v100, v100);
    float c11 = fmaf(fx, v111 - v110, v110);
    float c0  = fmaf(fy, c01 - c00, c00);
    float c1  = fmaf(fy, c11 - c10, c10);
    return fmaf(fz, c1 - c0, c0);
}

// half-wave dword-pair sampling: lane handles channels (2cp, 2cp+1) of point p.
// 8 dword gathers (each: half-wave covers one full 64-ch corner line = 128B).
__device__ __forceinline__ void sample_pair(const unsigned* __restrict__ xtb32,
                                            ushort* __restrict__ stage,
                                            int cp, int p,
                                            float nx, float ny, float nz) {
    float ix = fminf(fmaxf((nx + 1.0f) * 31.5f, 0.0f), 63.0f);
    float iy = fminf(fmaxf((ny + 1.0f) * 31.5f, 0.0f), 63.0f);
    float iz = fminf(fmaxf((nz + 1.0f) * 31.5f, 0.0f), 63.0f);
    float fx0 = floorf(ix), fy0 = floorf(iy), fz0 = floorf(iz);
    int x0 = (int)fx0, y0 = (int)fy0, z0 = (int)fz0;
    float fx = ix - fx0, fy = iy - fy0, fz = iz - fz0;
    int dx = (x0 < 63) ? 32 : 0;          // +1 in x = +32 dwords (64 ushorts)
    int dy = (y0 < 63) ? 2048 : 0;        // +1 in y
    int dz = (z0 < 63) ? 131072 : 0;      // +1 in z
    const unsigned* r = xtb32 + ((((z0 << 12) + (y0 << 6) + x0) << 5) + cp);
    unsigned u000 = r[0],       u001 = r[dx];
    unsigned u010 = r[dy],      u011 = r[dy + dx];
    unsigned u100 = r[dz],      u101 = r[dz + dx];
    unsigned u110 = r[dz + dy], u111 = r[dz + dy + dx];
    float sa = tri8(bf2f((ushort)u000), bf2f((ushort)u001),
                    bf2f((ushort)u010), bf2f((ushort)u011),
                    bf2f((ushort)u100), bf2f((ushort)u101),
                    bf2f((ushort)u110), bf2f((ushort)u111), fx, fy, fz);
    float sb = tri8(bf2f((ushort)(u000 >> 16)), bf2f((ushort)(u001 >> 16)),
                    bf2f((ushort)(u010 >> 16)), bf2f((ushort)(u011 >> 16)),
                    bf2f((ushort)(u100 >> 16)), bf2f((ushort)(u101 >> 16)),
                    bf2f((ushort)(u110 >> 16)), bf2f((ushort)(u111 >> 16)), fx, fy, fz);
    *(unsigned*)(stage + p * 104 + 2 * cp) =
        (unsigned)f2bf(sa) | ((unsigned)f2bf(sb) << 16);
}

// ---- fallback (channel-major f32) sampling ----
__device__ __forceinline__ float sample_cm(const float* __restrict__ xb,
                                           float gx, float gy, float gz) {
    float ix = fminf(fmaxf((gx + 1.0f) * 31.5f, 0.0f), 63.0f);
    float iy = fminf(fmaxf((gy + 1.0f) * 31.5f, 0.0f), 63.0f);
    float iz = fminf(fmaxf((gz + 1.0f) * 31.5f, 0.0f), 63.0f);
    float fx0 = floorf(ix), fy0 = floorf(iy), fz0 = floorf(iz);
    int x0 = (int)fx0, y0 = (int)fy0, z0 = (int)fz0;
    float fx = ix - fx0, fy = iy - fy0, fz = iz - fz0;
    int x1 = (x0 < 63) ? x0 + 1 : 63;
    int dy = (y0 < 63) ? 64 : 0;
    int dz = (z0 < 63) ? 4096 : 0;
    const float* r = xb + ((z0 << 12) + (y0 << 6));
    float v000 = r[x0],           v001 = r[x1];
    float v010 = r[x0 + dy],      v011 = r[x1 + dy];
    float v100 = r[x0 + dz],      v101 = r[x1 + dz];
    float v110 = r[x0 + dy + dz], v111 = r[x1 + dy + dz];
    return tri8(v000, v001, v010, v011, v100, v101, v110, v111, fx, fy, fz);
}

// ---------------- weight packing: B-fragment lane order, bf16 (unchanged) ----------------
__global__ void sb_pack(const float* __restrict__ shape_w, const float* __restrict__ shape_b,
                        const float* __restrict__ delta_w, const float* __restrict__ delta_b,
                        const float* __restrict__ ph_w, const float* __restrict__ ph_b,
                        const float* __restrict__ nh1_w, const float* __restrict__ nh1_b,
                        const float* __restrict__ nh2_w, char* __restrict__ wsb) {
    int tid = blockIdx.x * blockDim.x + threadIdx.x;
    int nt  = gridDim.x * blockDim.x;
    float*  bph = (float*)(wsb + BIAS_PH);
    float*  bn1 = (float*)(wsb + BIAS_N1);
    float*  bdl = (float*)(wsb + BIAS_DL);
    ushort* wph = (ushort*)(wsb + B_PH);
    ushort* wn1 = (ushort*)(wsb + B_N1);
    ushort* wdh = (ushort*)(wsb + B_DH);
    ushort* wdl = (ushort*)(wsb + B_DLO);
    ushort* wn2 = (ushort*)(wsb + B_N2);

    for (int e = tid; e < 64; e += nt) { bph[e] = ph_b[e]; bn1[e] = nh1_b[e]; }
    for (int e = tid; e < 32; e += nt) {
        float v = 0.0f;
        if (e < 24) {
            v = delta_b[e];
#pragma unroll
            for (int i = 0; i < 4; ++i) {   // fold shape_vec (constant) into bias, f32 exact
                float sv = 64.0f * (shape_w[i*4] + shape_w[i*4+1] + shape_w[i*4+2] + shape_w[i*4+3])
                         + shape_b[i];
                v += sv * delta_w[e * 71 + 67 + i];
            }
        }
        bdl[e] = v;
    }
    for (int e = tid; e < 6144; e += nt) {
        int frag = e >> 9, lane = (e >> 3) & 63, j = e & 7;
        int kt = frag >> 2, n = frag & 3;
        int k = kt * 32 + ((lane >> 4) << 3) + j;
        int col = n * 16 + (lane & 15);
        wph[e] = (k < 67) ? f2bf(ph_w[col * 67 + k])  : (ushort)0;
        wn1[e] = (k < 67) ? f2bf(nh1_w[col * 67 + k]) : (ushort)0;
    }
    for (int e = tid; e < 3072; e += nt) {
        int frag = e >> 9, lane = (e >> 3) & 63, j = e & 7;
        int kt = frag >> 1, n = frag & 1;
        int k = kt * 32 + ((lane >> 4) << 3) + j;
        int col = n * 16 + (lane & 15);
        float w = (col < 24 && k < 67) ? delta_w[col * 71 + k] : 0.0f;
        ushort hi = f2bf(w);
        wdh[e] = hi;
        wdl[e] = f2bf(w - bf2f(hi));
    }
    for (int e = tid; e < 36864; e += nt) {
        int frag = e >> 9, lane = (e >> 3) & 63, j = e & 7;
        int c9 = frag >> 3, kt = (frag >> 2) & 1, n = frag & 3;
        int k = kt * 32 + ((lane >> 4) << 3) + j;
        int c = n * 16 + (lane & 15);
        wn2[e] = f2bf(nh2_w[(c * 64 + k) * 9 + c9]);
    }
}

// ---------------- transpose x [B,C,64^3] f32 -> xt [B,64^3,C] bf16 (unchanged) ----------------
__global__ __launch_bounds__(256) void sb_transpose(const float* __restrict__ x,
                                                    ushort* __restrict__ xt) {
    __shared__ float tile[64][65];
    int blk = blockIdx.x;
    int b = blk >> 12, zy = blk & 4095;
    const float* __restrict__ src = x + ((size_t)b << 24) + zy * 64;
    unsigned* __restrict__ dst32 = (unsigned*)(xt + ((size_t)b << 24) + (size_t)zy * 4096);
    int t = threadIdx.x;
    int xx = t & 63, c0 = t >> 6;
#pragma unroll
    for (int i = 0; i < 16; ++i) {
        int c = i * 4 + c0;
        tile[c][xx] = src[((size_t)c << 18) + xx];
    }
    __syncthreads();
    int cp = t & 31, xs0 = t >> 5;
#pragma unroll
    for (int i = 0; i < 8; ++i) {
        int xs = i * 8 + xs0;
        unsigned lo = f2bf(tile[cp * 2][xs]);
        unsigned hi = f2bf(tile[cp * 2 + 1][xs]);
        dst32[xs * 32 + cp] = lo | (hi << 16);
    }
}

// ---------------- main MFMA kernel: 2 independent waves/block, NO barriers ----------------
// r14's register-slim body (split sweeps, pf parked in LDS, bias reloads; ~116 VGPR,
// zero spill) x r15's occupancy structure (2 barrier-free waves/block). No min-waves
// launch-bounds arg: hipcc's cap is aggressive and forces spill (r2/r13/r15 lesson).
__global__ __launch_bounds__(64 * WPB) void sb_main_mfma(
        const ushort* __restrict__ xt, const float* __restrict__ verts,
        const char* __restrict__ wsb, float* __restrict__ out) {
    __shared__ __align__(16) ushort stage_s[WPB][PT * 104];  // A tile [point][K..95]
    __shared__ __align__(16) ushort hst_s[WPB][PT * 72];     // gelu(h) A tile
    __shared__ float pfs_s[WPB][PT * 64];                    // parked point-head results
    __shared__ float cst_s[WPB][PT * 4];                     // vertex coords
    __shared__ float dls_s[WPB][PT * 32];                    // delta outputs

    const int tid  = threadIdx.x;
    const int wid  = tid >> 6, lane = tid & 63;
    const int l15 = lane & 15, lg = lane >> 4;
    const int half8 = (lane >> 5) * 8;                // sampling: point offset for half-wave
    const int cp = lane & 31;                         // sampling: channel pair
    const int tile = blockIdx.x * WPB + wid;          // NTILE % WPB == 0, no tail
    const int g0 = tile * PT;
    const int b  = g0 / Nc;
    const unsigned* __restrict__ xtb32 = (const unsigned*)(xt + ((size_t)b << 24));

    ushort* stage = stage_s[wid];
    ushort* hst   = hst_s[wid];
    float*  pfs   = pfs_s[wid];
    float*  cst   = cst_s[wid];
    float*  dls   = dls_s[wid];

    const float*  bph = (const float*)(wsb + BIAS_PH);
    const float*  bn1 = (const float*)(wsb + BIAS_N1);
    const float*  bdl = (const float*)(wsb + BIAS_DL);
    const ushort* Wph = (const ushort*)(wsb + B_PH);
    const ushort* Wn1 = (const ushort*)(wsb + B_N1);
    const ushort* Wdh = (const ushort*)(wsb + B_DH);
    const ushort* Wdl = (const ushort*)(wsb + B_DLO);
    const ushort* Wn2 = (const ushort*)(wsb + B_N2);

    // zero-init A tile (pad cols 72..103 are MFMA-read vs zero weights; NaN*0=NaN otherwise)
#pragma unroll
    for (int i = 0; i < (PT * 104) / 64; ++i) stage[i * 64 + lane] = 0;

    // init: verts -> cst + stage coord block (cols 64..71; 67.. zero, weights zero-padded)
    if (lane < PT) {
        const float* vp = verts + (size_t)(g0 + lane) * 3;
        float x = vp[0], y = vp[1], z = vp[2];
        cst[lane*4+0] = x; cst[lane*4+1] = y; cst[lane*4+2] = z;
        uint4 cw;
        cw.x = (unsigned)f2bf(x) | ((unsigned)f2bf(y) << 16);
        cw.y = (unsigned)f2bf(z);
        cw.z = 0u; cw.w = 0u;
        *(uint4*)(stage + lane * 104 + 64) = cw;
    }

    // ---- sample column 0: half-wave point split, 64 dword gathers ----
#pragma unroll 4
    for (int pp = 0; pp < 8; ++pp) {
        int p = half8 + pp;
        sample_pair(xtb32, stage, cp, p, cst[p*4+0], cst[p*4+1], cst[p*4+2]);
    }

    // ---- sweep 1: point head + delta (hi+lo), K=96; peak acc = 24 regs ----
    {
        f32x4 pf[4], dd[2];
#pragma unroll
        for (int n = 0; n < 4; ++n) {
            float bp = bph[n*16 + l15];
            pf[n] = (f32x4){bp, bp, bp, bp};
        }
#pragma unroll
        for (int n = 0; n < 2; ++n) {
            float bd = bdl[n*16 + l15];
            dd[n] = (f32x4){bd, bd, bd, bd};
        }
#pragma unroll
        for (int kt = 0; kt < 3; ++kt) {
            bf16x8 a = *(const bf16x8*)(stage + l15 * 104 + kt * 32 + lg * 8);
#pragma unroll
            for (int n = 0; n < 4; ++n) {
                bf16x8 bw = *(const bf16x8*)(Wph + ((kt*4 + n) << 9) + lane * 8);
                pf[n] = __builtin_amdgcn_mfma_f32_16x16x32_bf16(a, bw, pf[n], 0, 0, 0);
            }
#pragma unroll
            for (int n = 0; n < 2; ++n) {
                bf16x8 bh = *(const bf16x8*)(Wdh + ((kt*2 + n) << 9) + lane * 8);
                dd[n] = __builtin_amdgcn_mfma_f32_16x16x32_bf16(a, bh, dd[n], 0, 0, 0);
                bf16x8 bl = *(const bf16x8*)(Wdl + ((kt*2 + n) << 9) + lane * 8);
                dd[n] = __builtin_amdgcn_mfma_f32_16x16x32_bf16(a, bl, dd[n], 0, 0, 0);
            }
        }
        // D layout: row=(lg*4+r) [point], col=n*16+l15 ; park pf in LDS, dd in dls
#pragma unroll
        for (int n = 0; n < 2; ++n)
#pragma unroll
            for (int r = 0; r < 4; ++r)
                dls[(lg*4 + r) * 32 + n*16 + l15] = dd[n][r];
#pragma unroll
        for (int n = 0; n < 4; ++n)
#pragma unroll
            for (int r = 0; r < 4; ++r)
                pfs[(lg*4 + r) * 64 + n*16 + l15] = pf[n][r];
    }

    // ---- sweep 2: nh1 column 0, K=96; acc = 16 regs ----
    {
        f32x4 hh[4];
#pragma unroll
        for (int n = 0; n < 4; ++n) {
            float bh = bn1[n*16 + l15];
            hh[n] = (f32x4){bh, bh, bh, bh};
        }
#pragma unroll
        for (int kt = 0; kt < 3; ++kt) {
            bf16x8 a = *(const bf16x8*)(stage + l15 * 104 + kt * 32 + lg * 8);
#pragma unroll
            for (int n = 0; n < 4; ++n) {
                bf16x8 b1 = *(const bf16x8*)(Wn1 + ((kt*4 + n) << 9) + lane * 8);
                hh[n] = __builtin_amdgcn_mfma_f32_16x16x32_bf16(a, b1, hh[n], 0, 0, 0);
            }
        }
#pragma unroll
        for (int n = 0; n < 4; ++n)
#pragma unroll
            for (int r = 0; r < 4; ++r)
                hst[(lg*4 + r) * 72 + n*16 + l15] = f2bf(gelu_exact(hh[n][r]));
    }

    // ---- nh2 column 0 (K=64, 2 ksteps); nf persists (16 regs) ----
    f32x4 nf[4];
#pragma unroll
    for (int n = 0; n < 4; ++n) nf[n] = (f32x4){0.f, 0.f, 0.f, 0.f};
#pragma unroll
    for (int kt = 0; kt < 2; ++kt) {
        bf16x8 a = *(const bf16x8*)(hst + l15 * 72 + kt * 32 + lg * 8);
#pragma unroll
        for (int n = 0; n < 4; ++n) {
            bf16x8 bw = *(const bf16x8*)(Wn2 + ((kt*4 + n) << 9) + lane * 8);
            nf[n] = __builtin_amdgcn_mfma_f32_16x16x32_bf16(a, bw, nf[n], 0, 0, 0);
        }
    }

    // ---- neighbour columns 1..8 ----
    for (int k = 0; k < Kc; ++k) {
        // coord block cols 64..71 for this column
        if (lane < PT) {
            float x = cst[lane*4+0] + dls[lane*32 + 3*k + 0];
            float y = cst[lane*4+1] + dls[lane*32 + 3*k + 1];
            float z = cst[lane*4+2] + dls[lane*32 + 3*k + 2];
            uint4 cw;
            cw.x = (unsigned)f2bf(x) | ((unsigned)f2bf(y) << 16);
            cw.y = (unsigned)f2bf(z);
            cw.z = 0u; cw.w = 0u;
            *(uint4*)(stage + lane * 104 + 64) = cw;
        }
        // sample: half-wave point split, coords recomputed per lane (LDS broadcast)
#pragma unroll 4
        for (int pp = 0; pp < 8; ++pp) {
            int p = half8 + pp;
            float nx = cst[p*4+0] + dls[p*32 + 3*k + 0];
            float ny = cst[p*4+1] + dls[p*32 + 3*k + 1];
            float nz = cst[p*4+2] + dls[p*32 + 3*k + 2];
            sample_pair(xtb32, stage, cp, p, nx, ny, nz);
        }

        f32x4 hk[4];
#pragma unroll
        for (int n = 0; n < 4; ++n) {
            float bh = bn1[n*16 + l15];         // reload per column (L1-resident)
            hk[n] = (f32x4){bh, bh, bh, bh};
        }
#pragma unroll
        for (int kt = 0; kt < 3; ++kt) {
            bf16x8 a = *(const bf16x8*)(stage + l15 * 104 + kt * 32 + lg * 8);
#pragma unroll
            for (int n = 0; n < 4; ++n) {
                bf16x8 b1 = *(const bf16x8*)(Wn1 + ((kt*4 + n) << 9) + lane * 8);
                hk[n] = __builtin_amdgcn_mfma_f32_16x16x32_bf16(a, b1, hk[n], 0, 0, 0);
            }
        }
#pragma unroll
        for (int n = 0; n < 4; ++n)
#pragma unroll
            for (int r = 0; r < 4; ++r)
                hst[(lg*4 + r) * 72 + n*16 + l15] = f2bf(gelu_exact(hk[n][r]));

        const ushort* Wk = Wn2 + ((size_t)(k + 1) << 12);
#pragma unroll
        for (int kt = 0; kt < 2; ++kt) {
            bf16x8 a = *(const bf16x8*)(hst + l15 * 72 + kt * 32 + lg * 8);
#pragma unroll
            for (int n = 0; n < 4; ++n) {
                bf16x8 bw = *(const bf16x8*)(Wk + ((kt*4 + n) << 9) + lane * 8);
                nf[n] = __builtin_amdgcn_mfma_f32_16x16x32_bf16(a, bw, nf[n], 0, 0, 0);
            }
        }
    }

    // ---- store out[point][channel] = pfs + nf (contiguous rows) ----
#pragma unroll
    for (int n = 0; n < 4; ++n)
#pragma unroll
        for (int r = 0; r < 4; ++r)
            out[(size_t)(g0 + lg*4 + r) * 64 + n*16 + l15] =
                pfs[(lg*4 + r) * 64 + n*16 + l15] + nf[n][r];
}

// ---------------- correctness fallback (only if ws too small; slow, f32) ----------------
__global__ __launch_bounds__(64) void sb_fallback(
        const float* __restrict__ x, const float* __restrict__ verts,
        const float* __restrict__ shape_w, const float* __restrict__ shape_b,
        const float* __restrict__ delta_w, const float* __restrict__ delta_b,
        const float* __restrict__ ph_w, const float* __restrict__ ph_b,
        const float* __restrict__ nh1_w, const float* __restrict__ nh1_b,
        const float* __restrict__ nh2_w, float* __restrict__ out) {
    __shared__ float cp[72];
    __shared__ float hcol[64];
    __shared__ float dl[24];
    int lane = threadIdx.x;
    int g = blockIdx.x;
    int b = g / Nc;
    const float* xb = x + ((size_t)(b * 64 + lane) << 18);
    float vx = verts[g*3], vy = verts[g*3+1], vz = verts[g*3+2];
    cp[lane] = sample_cm(xb, vx, vy, vz);
    if (lane < 8) {
        float v = 0.0f;
        if      (lane == 0) v = vx;
        else if (lane == 1) v = vy;
        else if (lane == 2) v = vz;
        else if (lane < 7) {
            int i = lane - 3;
            v = 64.0f*(shape_w[i*4]+shape_w[i*4+1]+shape_w[i*4+2]+shape_w[i*4+3]) + shape_b[i];
        }
        cp[64 + lane] = v;
    }
    __syncthreads();
    float pfv = ph_b[lane];
    for (int j = 0; j < 67; ++j) pfv += ph_w[lane*67 + j] * cp[j];
    if (lane < 24) {
        float s = delta_b[lane];
        for (int j = 0; j < 71; ++j) s += delta_w[lane*71 + j] * cp[j];
        dl[lane] = s;
    }
    float h = nh1_b[lane];
    for (int j = 0; j < 67; ++j) h += nh1_w[lane*67 + j] * cp[j];
    hcol[lane] = gelu_exact(h);
    __syncthreads();
    float nfv = 0.0f;
    for (int c2 = 0; c2 < 64; ++c2) nfv += nh2_w[(lane*64 + c2)*9] * hcol[c2];
    for (int k = 0; k < 8; ++k) {
        __syncthreads();
        float nx = vx + dl[3*k], ny = vy + dl[3*k+1], nz = vz + dl[3*k+2];
        cp[lane] = sample_cm(xb, nx, ny, nz);
        if (lane < 3) cp[64 + lane] = (lane == 0) ? nx : (lane == 1) ? ny : nz;
        __syncthreads();
        float hv = nh1_b[lane];
        for (int j = 0; j < 67; ++j) hv += nh1_w[lane*67 + j] * cp[j];
        hcol[lane] = gelu_exact(hv);
        __syncthreads();
        for (int c2 = 0; c2 < 64; ++c2) nfv += nh2_w[(lane*64 + c2)*9 + k + 1] * hcol[c2];
    }
    out[(size_t)g * 64 + lane] = pfv + nfv;
}

// ---------------- launch ----------------
extern "C" void kernel_launch(void* const* d_in, const int* in_sizes, int n_in,
                              void* d_out, int out_size, void* d_ws, size_t ws_size,
                              hipStream_t stream) {
    const float* x       = (const float*)d_in[0];
    const float* verts   = (const float*)d_in[1];
    const float* shape_w = (const float*)d_in[2];
    const float* shape_b = (const float*)d_in[3];
    const float* delta_w = (const float*)d_in[4];
    const float* delta_b = (const float*)d_in[5];
    const float* ph_w    = (const float*)d_in[6];
    const float* ph_b    = (const float*)d_in[7];
    const float* nh1_w   = (const float*)d_in[8];
    const float* nh1_b   = (const float*)d_in[9];
    const float* nh2_w   = (const float*)d_in[10];
    float* out = (float*)d_out;
    char*  wsb = (char*)d_ws;

    const size_t need = XT_BYTE + XT_USHORTS * 2;
    if (ws_size >= need) {
        ushort* xt = (ushort*)(wsb + XT_BYTE);
        sb_pack<<<96, 256, 0, stream>>>(shape_w, shape_b, delta_w, delta_b,
                                        ph_w, ph_b, nh1_w, nh1_b, nh2_w, wsb);
        sb_transpose<<<Bc * 4096, 256, 0, stream>>>(x, xt);
        sb_main_mfma<<<NBLK2, 64 * WPB, 0, stream>>>(xt, verts, wsb, out);
    } else {
        sb_fallback<<<Bc * Nc, 64, 0, stream>>>(x, verts, shape_w, shape_b, delta_w, delta_b,
                                                ph_w, ph_b, nh1_w, nh1_b, nh2_w, out);
    }
}

// Round 17
// 215.893 us; speedup vs baseline: 1.5688x; 1.5688x over previous
//
#include <hip/hip_runtime.h>
#include <math.h>

// ---------------- problem constants ----------------
constexpr int Bc = 2, Cc = 64, Nc = 50000, Kc = 8;
constexpr int PT = 16;                       // points per wave (MFMA M dim)
constexpr int NBLK = (Bc * Nc) / PT;         // 6250, exact

// ---------------- ws byte layout (same as round 8) ----------------
constexpr int BIAS_PH = 16;                  // f32[64]
constexpr int BIAS_N1 = 272;                 // f32[64]
constexpr int BIAS_DL = 528;                 // f32[32] (sv folded, padded)
constexpr int B_PH  = 1024;                  // 12 frags * 1KB
constexpr int B_N1  = 13312;                 // 12 frags
constexpr int B_DH  = 25600;                 // 6 frags (delta hi)
constexpr int B_DLO = 31744;                 // 6 frags (delta lo)
constexpr int B_N2  = 37888;                 // 72 frags -> ends 111616
constexpr size_t XT_BYTE = 262144;           // bf16 volume starts here
constexpr size_t XT_USHORTS = (size_t)Bc * 64 * 64 * 64 * 64;

using bf16x8 = __attribute__((ext_vector_type(8))) short;
using f32x4  = __attribute__((ext_vector_type(4))) float;

// ---------------- helpers ----------------
__device__ __forceinline__ float gelu_exact(float v) {
    return 0.5f * v * (1.0f + erff(v * 0.70710678118654752f));
}
// fast GELU (tanh/sigmoid form): v * sigmoid(1.59576912*(v + 0.044715 v^3)).
// max deviation from exact-erf GELU ~2e-3; saturates safely at +/-inf.
__device__ __forceinline__ float gelu_fast(float v) {
    float u = fmaf(0.044715f * v * v, v, v);
    float s = 1.0f / (1.0f + __expf(-1.5957691216057308f * u));
    return v * s;
}
__device__ __forceinline__ ushort f2bf(float f) {           // RNE f32 -> bf16 bits
    unsigned u = __float_as_uint(f);
    unsigned r = (u + 0x7FFFu + ((u >> 16) & 1u)) >> 16;
    return (ushort)r;
}
__device__ __forceinline__ float bf2f(ushort u) {
    return __uint_as_float(((unsigned)u) << 16);
}
__device__ __forceinline__ float tri8(float v000, float v001, float v010, float v011,
                                      float v100, float v101, float v110, float v111,
                                      float fx, float fy, float fz) {
    float c00 = fmaf(fx, v001 - v000, v000);
    float c01 = fmaf(fx, v011 - v010, v010);
    float c10 = fmaf(fx, v101 - v100, v100);
    float c11 = fmaf(fx, v101 - v100, v100);  // placeholder overwritten below
    c11 = fmaf(fx, v111 - v110, v110);
    float c0  = fmaf(fy, c01 - c00, c00);
    float c1  = fmaf(fy, c11 - c10, c10);
    return fmaf(fz, c1 - c0, c0);
}

// per-point sampling precompute (done once by lanes 0..15 per column):
// smp[p] = {base_dword, dx, dy, dz, fx, fy, fz, pad}
__device__ __forceinline__ void precompute_pt(int* __restrict__ smp, int p,
                                              float nx, float ny, float nz) {
    float ix = fminf(fmaxf((nx + 1.0f) * 31.5f, 0.0f), 63.0f);
    float iy = fminf(fmaxf((ny + 1.0f) * 31.5f, 0.0f), 63.0f);
    float iz = fminf(fmaxf((nz + 1.0f) * 31.5f, 0.0f), 63.0f);
    float fx0 = floorf(ix), fy0 = floorf(iy), fz0 = floorf(iz);
    int x0 = (int)fx0, y0 = (int)fy0, z0 = (int)fz0;
    smp[p*8+0] = ((z0 << 12) + (y0 << 6) + x0) << 5;   // dword offset of corner000 line
    smp[p*8+1] = (x0 < 63) ? 32 : 0;                   // +1 x = +32 dwords
    smp[p*8+2] = (y0 < 63) ? 2048 : 0;
    smp[p*8+3] = (z0 < 63) ? 131072 : 0;
    smp[p*8+4] = __float_as_int(ix - fx0);
    smp[p*8+5] = __float_as_int(iy - fy0);
    smp[p*8+6] = __float_as_int(iz - fz0);
}

// half-wave dword-pair sampling using precomputed coords (LDS broadcast reads).
__device__ __forceinline__ void sample_pair2(const unsigned* __restrict__ xtb32,
                                             ushort* __restrict__ stage,
                                             const int* __restrict__ smp,
                                             int cp, int p) {
    const int* s = smp + p * 8;
    int base = s[0], dx = s[1], dy = s[2], dz = s[3];
    float fx = __int_as_float(s[4]);
    float fy = __int_as_float(s[5]);
    float fz = __int_as_float(s[6]);
    const unsigned* r = xtb32 + base + cp;
    unsigned u000 = r[0],       u001 = r[dx];
    unsigned u010 = r[dy],      u011 = r[dy + dx];
    unsigned u100 = r[dz],      u101 = r[dz + dx];
    unsigned u110 = r[dz + dy], u111 = r[dz + dy + dx];
    float sa = tri8(bf2f((ushort)u000), bf2f((ushort)u001),
                    bf2f((ushort)u010), bf2f((ushort)u011),
                    bf2f((ushort)u100), bf2f((ushort)u101),
                    bf2f((ushort)u110), bf2f((ushort)u111), fx, fy, fz);
    float sb = tri8(bf2f((ushort)(u000 >> 16)), bf2f((ushort)(u001 >> 16)),
                    bf2f((ushort)(u010 >> 16)), bf2f((ushort)(u011 >> 16)),
                    bf2f((ushort)(u100 >> 16)), bf2f((ushort)(u101 >> 16)),
                    bf2f((ushort)(u110 >> 16)), bf2f((ushort)(u111 >> 16)), fx, fy, fz);
    *(unsigned*)(stage + p * 104 + 2 * cp) =
        (unsigned)f2bf(sa) | ((unsigned)f2bf(sb) << 16);
}

// ---- fallback (channel-major f32) sampling ----
__device__ __forceinline__ float sample_cm(const float* __restrict__ xb,
                                           float gx, float gy, float gz) {
    float ix = fminf(fmaxf((gx + 1.0f) * 31.5f, 0.0f), 63.0f);
    float iy = fminf(fmaxf((gy + 1.0f) * 31.5f, 0.0f), 63.0f);
    float iz = fminf(fmaxf((gz + 1.0f) * 31.5f, 0.0f), 63.0f);
    float fx0 = floorf(ix), fy0 = floorf(iy), fz0 = floorf(iz);
    int x0 = (int)fx0, y0 = (int)fy0, z0 = (int)fz0;
    float fx = ix - fx0, fy = iy - fy0, fz = iz - fz0;
    int x1 = (x0 < 63) ? x0 + 1 : 63;
    int dy = (y0 < 63) ? 64 : 0;
    int dz = (z0 < 63) ? 4096 : 0;
    const float* r = xb + ((z0 << 12) + (y0 << 6));
    float v000 = r[x0],           v001 = r[x1];
    float v010 = r[x0 + dy],      v011 = r[x1 + dy];
    float v100 = r[x0 + dz],      v101 = r[x1 + dz];
    float v110 = r[x0 + dy + dz], v111 = r[x1 + dy + dz];
    float c00 = fmaf(fx, v001 - v000, v000);
    float c01 = fmaf(fx, v011 - v010, v010);
    float c10 = fmaf(fx, v101 - v100, v100);
    float c11 = fmaf(fx, v111 - v110, v110);
    float c0  = fmaf(fy, c01 - c00, c00);
    float c1  = fmaf(fy, c11 - c10, c10);
    return fmaf(fz, c1 - c0, c0);
}

// ---------------- weight packing: B-fragment lane order, bf16 (unchanged) ----------------
__global__ void sb_pack(const float* __restrict__ shape_w, const float* __restrict__ shape_b,
                        const float* __restrict__ delta_w, const float* __restrict__ delta_b,
                        const float* __restrict__ ph_w, const float* __restrict__ ph_b,
                        const float* __restrict__ nh1_w, const float* __restrict__ nh1_b,
                        const float* __restrict__ nh2_w, char* __restrict__ wsb) {
    int tid = blockIdx.x * blockDim.x + threadIdx.x;
    int nt  = gridDim.x * blockDim.x;
    float*  bph = (float*)(wsb + BIAS_PH);
    float*  bn1 = (float*)(wsb + BIAS_N1);
    float*  bdl = (float*)(wsb + BIAS_DL);
    ushort* wph = (ushort*)(wsb + B_PH);
    ushort* wn1 = (ushort*)(wsb + B_N1);
    ushort* wdh = (ushort*)(wsb + B_DH);
    ushort* wdl = (ushort*)(wsb + B_DLO);
    ushort* wn2 = (ushort*)(wsb + B_N2);

    for (int e = tid; e < 64; e += nt) { bph[e] = ph_b[e]; bn1[e] = nh1_b[e]; }
    for (int e = tid; e < 32; e += nt) {
        float v = 0.0f;
        if (e < 24) {
            v = delta_b[e];
#pragma unroll
            for (int i = 0; i < 4; ++i) {   // fold shape_vec (constant) into bias, f32 exact
                float sv = 64.0f * (shape_w[i*4] + shape_w[i*4+1] + shape_w[i*4+2] + shape_w[i*4+3])
                         + shape_b[i];
                v += sv * delta_w[e * 71 + 67 + i];
            }
        }
        bdl[e] = v;
    }
    for (int e = tid; e < 6144; e += nt) {
        int frag = e >> 9, lane = (e >> 3) & 63, j = e & 7;
        int kt = frag >> 2, n = frag & 3;
        int k = kt * 32 + ((lane >> 4) << 3) + j;
        int col = n * 16 + (lane & 15);
        wph[e] = (k < 67) ? f2bf(ph_w[col * 67 + k])  : (ushort)0;
        wn1[e] = (k < 67) ? f2bf(nh1_w[col * 67 + k]) : (ushort)0;
    }
    for (int e = tid; e < 3072; e += nt) {
        int frag = e >> 9, lane = (e >> 3) & 63, j = e & 7;
        int kt = frag >> 1, n = frag & 1;
        int k = kt * 32 + ((lane >> 4) << 3) + j;
        int col = n * 16 + (lane & 15);
        float w = (col < 24 && k < 67) ? delta_w[col * 71 + k] : 0.0f;
        ushort hi = f2bf(w);
        wdh[e] = hi;
        wdl[e] = f2bf(w - bf2f(hi));
    }
    for (int e = tid; e < 36864; e += nt) {
        int frag = e >> 9, lane = (e >> 3) & 63, j = e & 7;
        int c9 = frag >> 3, kt = (frag >> 2) & 1, n = frag & 3;
        int k = kt * 32 + ((lane >> 4) << 3) + j;
        int c = n * 16 + (lane & 15);
        wn2[e] = f2bf(nh2_w[(c * 64 + k) * 9 + c9]);
    }
}

// ---------------- transpose x [B,C,64^3] f32 -> xt [B,64^3,C] bf16 (unchanged) ----------------
__global__ __launch_bounds__(256) void sb_transpose(const float* __restrict__ x,
                                                    ushort* __restrict__ xt) {
    __shared__ float tile[64][65];
    int blk = blockIdx.x;
    int b = blk >> 12, zy = blk & 4095;
    const float* __restrict__ src = x + ((size_t)b << 24) + zy * 64;
    unsigned* __restrict__ dst32 = (unsigned*)(xt + ((size_t)b << 24) + (size_t)zy * 4096);
    int t = threadIdx.x;
    int xx = t & 63, c0 = t >> 6;
#pragma unroll
    for (int i = 0; i < 16; ++i) {
        int c = i * 4 + c0;
        tile[c][xx] = src[((size_t)c << 18) + xx];
    }
    __syncthreads();
    int cp = t & 31, xs0 = t >> 5;
#pragma unroll
    for (int i = 0; i < 8; ++i) {
        int xs = i * 8 + xs0;
        unsigned lo = f2bf(tile[cp * 2][xs]);
        unsigned hi = f2bf(tile[cp * 2 + 1][xs]);
        dst32[xs * 32 + cp] = lo | (hi << 16);
    }
}

// ---------------- main MFMA kernel: 1 wave = 16 points (r14 structure) ----------------
// + per-point coord precompute in LDS (lanes 0..15, once per column)
// + fast-sigmoid GELU  + setprio around MFMA clusters.
__global__ __launch_bounds__(64, 6) void sb_main_mfma(
        const ushort* __restrict__ xt, const float* __restrict__ verts,
        const char* __restrict__ wsb, float* __restrict__ out) {
    __shared__ __align__(16) ushort stage[PT * 104];  // A tile [point][K..95], pad stride 104
    __shared__ __align__(16) ushort hst[PT * 72];     // gelu(h) A tile
    __shared__ float pfs[PT * 64];                    // parked point-head results (4 KB)
    __shared__ float cst[PT * 4];                     // vertex coords
    __shared__ float dls[PT * 32];                    // delta outputs
    __shared__ __align__(16) int smp[PT * 8];         // per-point sampling params

    const int lane = threadIdx.x;
    const int l15 = lane & 15, lg = lane >> 4;
    const int half8 = (lane >> 5) * 8;                // sampling: point offset for half-wave
    const int cp = lane & 31;                         // sampling: channel pair
    const int g0 = blockIdx.x * PT;
    const int b  = g0 / Nc;
    const unsigned* __restrict__ xtb32 = (const unsigned*)(xt + ((size_t)b << 24));

    const float*  bph = (const float*)(wsb + BIAS_PH);
    const float*  bn1 = (const float*)(wsb + BIAS_N1);
    const float*  bdl = (const float*)(wsb + BIAS_DL);
    const ushort* Wph = (const ushort*)(wsb + B_PH);
    const ushort* Wn1 = (const ushort*)(wsb + B_N1);
    const ushort* Wdh = (const ushort*)(wsb + B_DH);
    const ushort* Wdl = (const ushort*)(wsb + B_DLO);
    const ushort* Wn2 = (const ushort*)(wsb + B_N2);

    // zero-init A tile (pad cols 72..103 are MFMA-read vs zero weights; NaN*0=NaN otherwise)
#pragma unroll
    for (int i = 0; i < (PT * 104) / 64; ++i) stage[i * 64 + lane] = 0;

    // init: verts -> cst + stage coord block + sampling params (lanes 0..15)
    if (lane < PT) {
        const float* vp = verts + (size_t)(g0 + lane) * 3;
        float x = vp[0], y = vp[1], z = vp[2];
        cst[lane*4+0] = x; cst[lane*4+1] = y; cst[lane*4+2] = z;
        uint4 cw;
        cw.x = (unsigned)f2bf(x) | ((unsigned)f2bf(y) << 16);
        cw.y = (unsigned)f2bf(z);
        cw.z = 0u; cw.w = 0u;
        *(uint4*)(stage + lane * 104 + 64) = cw;
        precompute_pt(smp, lane, x, y, z);
    }
    __syncthreads();

    // ---- sample column 0: half-wave point split, precomputed coords ----
#pragma unroll 4
    for (int pp = 0; pp < 8; ++pp)
        sample_pair2(xtb32, stage, smp, cp, half8 + pp);
    __syncthreads();

    // ---- sweep 1: point head + delta (hi+lo), K=96; peak acc = 24 regs ----
    {
        f32x4 pf[4], dd[2];
#pragma unroll
        for (int n = 0; n < 4; ++n) {
            float bp = bph[n*16 + l15];
            pf[n] = (f32x4){bp, bp, bp, bp};
        }
#pragma unroll
        for (int n = 0; n < 2; ++n) {
            float bd = bdl[n*16 + l15];
            dd[n] = (f32x4){bd, bd, bd, bd};
        }
        __builtin_amdgcn_s_setprio(1);
#pragma unroll
        for (int kt = 0; kt < 3; ++kt) {
            bf16x8 a = *(const bf16x8*)(stage + l15 * 104 + kt * 32 + lg * 8);
#pragma unroll
            for (int n = 0; n < 4; ++n) {
                bf16x8 bw = *(const bf16x8*)(Wph + ((kt*4 + n) << 9) + lane * 8);
                pf[n] = __builtin_amdgcn_mfma_f32_16x16x32_bf16(a, bw, pf[n], 0, 0, 0);
            }
#pragma unroll
            for (int n = 0; n < 2; ++n) {
                bf16x8 bh = *(const bf16x8*)(Wdh + ((kt*2 + n) << 9) + lane * 8);
                dd[n] = __builtin_amdgcn_mfma_f32_16x16x32_bf16(a, bh, dd[n], 0, 0, 0);
                bf16x8 bl = *(const bf16x8*)(Wdl + ((kt*2 + n) << 9) + lane * 8);
                dd[n] = __builtin_amdgcn_mfma_f32_16x16x32_bf16(a, bl, dd[n], 0, 0, 0);
            }
        }
        __builtin_amdgcn_s_setprio(0);
        // D layout: row=(lg*4+r) [point], col=n*16+l15 ; park pf in LDS, dd in dls
#pragma unroll
        for (int n = 0; n < 2; ++n)
#pragma unroll
            for (int r = 0; r < 4; ++r)
                dls[(lg*4 + r) * 32 + n*16 + l15] = dd[n][r];
#pragma unroll
        for (int n = 0; n < 4; ++n)
#pragma unroll
            for (int r = 0; r < 4; ++r)
                pfs[(lg*4 + r) * 64 + n*16 + l15] = pf[n][r];
    }

    // ---- sweep 2: nh1 column 0, K=96; acc = 16 regs ----
    {
        f32x4 hh[4];
#pragma unroll
        for (int n = 0; n < 4; ++n) {
            float bh = bn1[n*16 + l15];
            hh[n] = (f32x4){bh, bh, bh, bh};
        }
        __builtin_amdgcn_s_setprio(1);
#pragma unroll
        for (int kt = 0; kt < 3; ++kt) {
            bf16x8 a = *(const bf16x8*)(stage + l15 * 104 + kt * 32 + lg * 8);
#pragma unroll
            for (int n = 0; n < 4; ++n) {
                bf16x8 b1 = *(const bf16x8*)(Wn1 + ((kt*4 + n) << 9) + lane * 8);
                hh[n] = __builtin_amdgcn_mfma_f32_16x16x32_bf16(a, b1, hh[n], 0, 0, 0);
            }
        }
        __builtin_amdgcn_s_setprio(0);
#pragma unroll
        for (int n = 0; n < 4; ++n)
#pragma unroll
            for (int r = 0; r < 4; ++r)
                hst[(lg*4 + r) * 72 + n*16 + l15] = f2bf(gelu_fast(hh[n][r]));
    }
    __syncthreads();

    // ---- nh2 column 0 (K=64, 2 ksteps); nf persists (16 regs) ----
    f32x4 nf[4];
#pragma unroll
    for (int n = 0; n < 4; ++n) nf[n] = (f32x4){0.f, 0.f, 0.f, 0.f};
    __builtin_amdgcn_s_setprio(1);
#pragma unroll
    for (int kt = 0; kt < 2; ++kt) {
        bf16x8 a = *(const bf16x8*)(hst + l15 * 72 + kt * 32 + lg * 8);
#pragma unroll
        for (int n = 0; n < 4; ++n) {
            bf16x8 bw = *(const bf16x8*)(Wn2 + ((kt*4 + n) << 9) + lane * 8);
            nf[n] = __builtin_amdgcn_mfma_f32_16x16x32_bf16(a, bw, nf[n], 0, 0, 0);
        }
    }
    __builtin_amdgcn_s_setprio(0);

    // ---- neighbour columns 1..8 ----
    for (int k = 0; k < Kc; ++k) {
        // per-point coord block + sampling params for this column (lanes 0..15)
        if (lane < PT) {
            float x = cst[lane*4+0] + dls[lane*32 + 3*k + 0];
            float y = cst[lane*4+1] + dls[lane*32 + 3*k + 1];
            float z = cst[lane*4+2] + dls[lane*32 + 3*k + 2];
            uint4 cw;
            cw.x = (unsigned)f2bf(x) | ((unsigned)f2bf(y) << 16);
            cw.y = (unsigned)f2bf(z);
            cw.z = 0u; cw.w = 0u;
            *(uint4*)(stage + lane * 104 + 64) = cw;
            precompute_pt(smp, lane, x, y, z);
        }
        // sample: half-wave point split, precomputed coords (LDS broadcast)
#pragma unroll 4
        for (int pp = 0; pp < 8; ++pp)
            sample_pair2(xtb32, stage, smp, cp, half8 + pp);
        __syncthreads();

        f32x4 hk[4];
#pragma unroll
        for (int n = 0; n < 4; ++n) {
            float bh = bn1[n*16 + l15];         // reload per column (L1-resident)
            hk[n] = (f32x4){bh, bh, bh, bh};
        }
        __builtin_amdgcn_s_setprio(1);
#pragma unroll
        for (int kt = 0; kt < 3; ++kt) {
            bf16x8 a = *(const bf16x8*)(stage + l15 * 104 + kt * 32 + lg * 8);
#pragma unroll
            for (int n = 0; n < 4; ++n) {
                bf16x8 b1 = *(const bf16x8*)(Wn1 + ((kt*4 + n) << 9) + lane * 8);
                hk[n] = __builtin_amdgcn_mfma_f32_16x16x32_bf16(a, b1, hk[n], 0, 0, 0);
            }
        }
        __builtin_amdgcn_s_setprio(0);
#pragma unroll
        for (int n = 0; n < 4; ++n)
#pragma unroll
            for (int r = 0; r < 4; ++r)
                hst[(lg*4 + r) * 72 + n*16 + l15] = f2bf(gelu_fast(hk[n][r]));
        __syncthreads();

        const ushort* Wk = Wn2 + ((size_t)(k + 1) << 12);
        __builtin_amdgcn_s_setprio(1);
#pragma unroll
        for (int kt = 0; kt < 2; ++kt) {
            bf16x8 a = *(const bf16x8*)(hst + l15 * 72 + kt * 32 + lg * 8);
#pragma unroll
            for (int n = 0; n < 4; ++n) {
                bf16x8 bw = *(const bf16x8*)(Wk + ((kt*4 + n) << 9) + lane * 8);
                nf[n] = __builtin_amdgcn_mfma_f32_16x16x32_bf16(a, bw, nf[n], 0, 0, 0);
            }
        }
        __builtin_amdgcn_s_setprio(0);
    }

    // ---- store out[point][channel] = pfs + nf (contiguous rows) ----
#pragma unroll
    for (int n = 0; n < 4; ++n)
#pragma unroll
        for (int r = 0; r < 4; ++r)
            out[(size_t)(g0 + lg*4 + r) * 64 + n*16 + l15] =
                pfs[(lg*4 + r) * 64 + n*16 + l15] + nf[n][r];
}

// ---------------- correctness fallback (only if ws too small; slow, f32) ----------------
__global__ __launch_bounds__(64) void sb_fallback(
        const float* __restrict__ x, const float* __restrict__ verts,
        const float* __restrict__ shape_w, const float* __restrict__ shape_b,
        const float* __restrict__ delta_w, const float* __restrict__ delta_b,
        const float* __restrict__ ph_w, const float* __restrict__ ph_b,
        const float* __restrict__ nh1_w, const float* __restrict__ nh1_b,
        const float* __restrict__ nh2_w, float* __restrict__ out) {
    __shared__ float cp[72];
    __shared__ float hcol[64];
    __shared__ float dl[24];
    int lane = threadIdx.x;
    int g = blockIdx.x;
    int b = g / Nc;
    const float* xb = x + ((size_t)(b * 64 + lane) << 18);
    float vx = verts[g*3], vy = verts[g*3+1], vz = verts[g*3+2];
    cp[lane] = sample_cm(xb, vx, vy, vz);
    if (lane < 8) {
        float v = 0.0f;
        if      (lane == 0) v = vx;
        else if (lane == 1) v = vy;
        else if (lane == 2) v = vz;
        else if (lane < 7) {
            int i = lane - 3;
            v = 64.0f*(shape_w[i*4]+shape_w[i*4+1]+shape_w[i*4+2]+shape_w[i*4+3]) + shape_b[i];
        }
        cp[64 + lane] = v;
    }
    __syncthreads();
    float pfv = ph_b[lane];
    for (int j = 0; j < 67; ++j) pfv += ph_w[lane*67 + j] * cp[j];
    if (lane < 24) {
        float s = delta_b[lane];
        for (int j = 0; j < 71; ++j) s += delta_w[lane*71 + j] * cp[j];
        dl[lane] = s;
    }
    float h = nh1_b[lane];
    for (int j = 0; j < 67; ++j) h += nh1_w[lane*67 + j] * cp[j];
    hcol[lane] = gelu_exact(h);
    __syncthreads();
    float nfv = 0.0f;
    for (int c2 = 0; c2 < 64; ++c2) nfv += nh2_w[(lane*64 + c2)*9] * hcol[c2];
    for (int k = 0; k < 8; ++k) {
        __syncthreads();
        float nx = vx + dl[3*k], ny = vy + dl[3*k+1], nz = vz + dl[3*k+2];
        cp[lane] = sample_cm(xb, nx, ny, nz);
        if (lane < 3) cp[64 + lane] = (lane == 0) ? nx : (lane == 1) ? ny : nz;
        __syncthreads();
        float hv = nh1_b[lane];
        for (int j = 0; j < 67; ++j) hv += nh1_w[lane*67 + j] * cp[j];
        hcol[lane] = gelu_exact(hv);
        __syncthreads();
        for (int c2 = 0; c2 < 64; ++c2) nfv += nh2_w[(lane*64 + c2)*9 + k + 1] * hcol[c2];
    }
    out[(size_t)g * 64 + lane] = pfv + nfv;
}

// ---------------- launch ----------------
extern "C" void kernel_launch(void* const* d_in, const int* in_sizes, int n_in,
                              void* d_out, int out_size, void* d_ws, size_t ws_size,
                              hipStream_t stream) {
    const float* x       = (const float*)d_in[0];
    const float* verts   = (const float*)d_in[1];
    const float* shape_w = (const float*)d_in[2];
    const float* shape_b = (const float*)d_in[3];
    const float* delta_w = (const float*)d_in[4];
    const float* delta_b = (const float*)d_in[5];
    const float* ph_w    = (const float*)d_in[6];
    const float* ph_b    = (const float*)d_in[7];
    const float* nh1_w   = (const float*)d_in[8];
    const float* nh1_b   = (const float*)d_in[9];
    const float* nh2_w   = (const float*)d_in[10];
    float* out = (float*)d_out;
    char*  wsb = (char*)d_ws;

    const size_t need = XT_BYTE + XT_USHORTS * 2;
    if (ws_size >= need) {
        ushort* xt = (ushort*)(wsb + XT_BYTE);
        sb_pack<<<96, 256, 0, stream>>>(shape_w, shape_b, delta_w, delta_b,
                                        ph_w, ph_b, nh1_w, nh1_b, nh2_w, wsb);
        sb_transpose<<<Bc * 4096, 256, 0, stream>>>(x, xt);
        sb_main_mfma<<<NBLK, 64, 0, stream>>>(xt, verts, wsb, out);
    } else {
        sb_fallback<<<Bc * Nc, 64, 0, stream>>>(x, verts, shape_w, shape_b, delta_w, delta_b,
                                                ph_w, ph_b, nh1_w, nh1_b, nh2_w, out);
    }
}